// Round 10
// baseline (246.523 us; speedup 1.0000x reference)
//
#include <hip/hip_runtime.h>

// SparseActivation: per row of D=2048 fp32, keep top K=204 by |x|, scale D/K.
//
// TWO-KERNEL SPLIT (round-9). Evidence through round 8: with adequate grid,
// duration is pinned at ~85us (2.3-2.4 TB/s) across EVERY in-wave structure
// (VALU work cut 2.7x, verified asm pipeline, depth 1/2/3) — in-wave
// scheduling is exhausted. The last untested structural property: every
// variant interleaves a 134MB read stream with a 131MB write stream while
// each wave serially holds its row (load->wait->search->store).
//   K1 threshold pass (READ-ONLY): 1 row/wave, bisection search, writes one
//      float per row to d_ws (64KB). No write stream. Rare tie-spanning rows
//      (prob ~0 on continuous data; handled exactly) write their output row
//      here and flag thr=-inf.
//   K2 apply pass (PURE STREAM): grid-stride |x|>=thr ? x*scale : 0.
//      Copy-shaped (no held state, no reduction) -> copy-class BW; input is
//      L3-hot from K1 (134MB < 256MB L3), so K2 is ~write-bound.
// Diagnostic: if K1 alone still caps at ~2.4 TB/s read-only, the cap is
// read-path latency -> roofline. If K1 hits 4-6 TB/s, R/W interference was
// the ~85us invariant's cause.
//
// Search (K1): exact K-th largest via bracket bisection on |x| (free |src|
// modifier on v_cmp). Warm-start probes near the N(0,1) expected K-th value
// (~1.648, k/n=0.1); every bracket update is backed by an exact count ->
// exact for ANY finite input. done-path (count==K at thr) guarantees
// {|x| >= thr} IS the exact top-K set, so K2's elementwise compare
// reproduces it exactly. Bracket closed => tie spans the boundary =>
// K1 resolves ranks by lowest-global-index (lax.top_k stability) itself.

constexpr int D_DIM = 2048;
constexpr int K_SEL = 204;     // int(2048 * 0.1)
constexpr int NT    = 256;     // 4 waves/block, one row per wave (K1)

typedef float f32x4 __attribute__((ext_vector_type(4)));

// Full-wave64 integer sum via DPP; returns total (uniform, via readlane 63).
__device__ __forceinline__ int dpp_reduce_add(int x) {
    x += __builtin_amdgcn_update_dpp(0, x, 0x111, 0xF, 0xF, true);  // row_shr:1
    x += __builtin_amdgcn_update_dpp(0, x, 0x112, 0xF, 0xF, true);  // row_shr:2
    x += __builtin_amdgcn_update_dpp(0, x, 0x114, 0xF, 0xF, true);  // row_shr:4
    x += __builtin_amdgcn_update_dpp(0, x, 0x118, 0xF, 0xF, true);  // row_shr:8
    x += __builtin_amdgcn_update_dpp(0, x, 0x142, 0xA, 0xF, false); // row_bcast:15
    x += __builtin_amdgcn_update_dpp(0, x, 0x143, 0xC, 0xF, false); // row_bcast:31
    return __builtin_amdgcn_readlane(x, 63);
}

// Exact wave-wide count of elements with |value| >= t (t > 0, finite data).
__device__ __forceinline__ int wave_count_ge(const f32x4 (&f)[8], float t) {
    int c0 = 0, c1 = 0, c2 = 0, c3 = 0;
#pragma unroll
    for (int b = 0; b < 8; ++b) {
        c0 += (__builtin_fabsf(f[b].x) >= t) ? 1 : 0;
        c1 += (__builtin_fabsf(f[b].y) >= t) ? 1 : 0;
        c2 += (__builtin_fabsf(f[b].z) >= t) ? 1 : 0;
        c3 += (__builtin_fabsf(f[b].w) >= t) ? 1 : 0;
    }
    return dpp_reduce_add((c0 + c1) + (c2 + c3));
}

// ---------------- K1: per-row threshold (read-only fast path) ---------------
__global__ __launch_bounds__(NT) void thresh_kernel(const float* __restrict__ x,
                                                    float* __restrict__ out,
                                                    float* __restrict__ thrws) {
    const int wave = threadIdx.x >> 6;
    const int lane = threadIdx.x & 63;
    const long long row = (long long)blockIdx.x * 4 + wave;

    const f32x4* xp = reinterpret_cast<const f32x4*>(x + row * D_DIM);
    f32x4 f[8];
#pragma unroll
    for (int b = 0; b < 8; ++b) f[b] = xp[b * 64 + lane];

    // Bracket invariant: count(>= lo) > K > count(>= hi)  (strict on lo: lo
    // only ever set when c > K; c == K early-exits as done).
    unsigned lo = 0u, hi = 0x80000000u;
    unsigned thr = 0u;
    bool done = false;

    // ---- Warm-start probe ladder (speed heuristic only; exact regardless) --
    {
        const int c = wave_count_ge(f, 1.6484375f);              // 0x3FD30000
        if (c == K_SEL) { thr = 0x3FD30000u; done = true; }
        else if (c > K_SEL) lo = 0x3FD30000u; else hi = 0x3FD30000u;
    }
    if (!done) {
        const unsigned p2 = (lo != 0u) ? 0x3FD60000u             // 1.671875
                                       : 0x3FD00000u;            // 1.625
        const int c = wave_count_ge(f, __uint_as_float(p2));
        if (c == K_SEL) { thr = p2; done = true; }
        else if (c > K_SEL) lo = p2; else hi = p2;
    }
    if (!done) {
        unsigned p3 = 0u;
        if (hi == 0x80000000u)      p3 = 0x3FE00000u;            // 1.75 (cap)
        else if (lo == 0u)          p3 = 0x3FC80000u;            // 1.5625 (floor)
        if (p3 != 0u) {
            const int c = wave_count_ge(f, __uint_as_float(p3));
            if (c == K_SEL) { thr = p3; done = true; }
            else if (c > K_SEL) lo = p3; else hi = p3;
        }
    }
    if (!done && lo == 0u) {   // very rare: K-th below 1.5625
        const int c = wave_count_ge(f, 1.0f);                    // 0x3F800000
        if (c == K_SEL) { thr = 0x3F800000u; done = true; }
        else if (c > K_SEL) lo = 0x3F800000u; else hi = 0x3F800000u;
    }

    // ---- Integer bisection of the bracket; early exit at exact count K. ----
#pragma unroll 1
    while (!done && (hi - lo) > 1u) {
        const unsigned mid = (lo + hi) >> 1;   // lo < mid < hi guaranteed
        const int c = wave_count_ge(f, __uint_as_float(mid));
        if (c == K_SEL) { thr = mid; done = true; }
        else if (c > K_SEL) lo = mid; else hi = mid;
    }

    if (done) {
        // count(|x| >= thr) == K exactly -> K2's compare selects exact top-K.
        if (lane == 0) thrws[row] = __uint_as_float(thr);
        return;
    }

    // RARE: tie spans the boundary (duplicated |x| at the K-th value).
    // lo is the exact K-th largest pattern. Resolve ranks here, write the
    // output row directly, and flag this row so K2 skips its stores.
    const float scale = 2048.0f / 204.0f;
    const float Tf = __uint_as_float(lo);
    int ge_pack = 0;
#pragma unroll
    for (int b = 0; b < 8; ++b) {
        ge_pack += (__builtin_fabsf(f[b].x) > Tf) ? 1 : 0;
        ge_pack += (__builtin_fabsf(f[b].y) > Tf) ? 1 : 0;
        ge_pack += (__builtin_fabsf(f[b].z) > Tf) ? 1 : 0;
        ge_pack += (__builtin_fabsf(f[b].w) > Tf) ? 1 : 0;
        ge_pack += (__builtin_fabsf(f[b].x) == Tf) ? (1 << 16) : 0;
        ge_pack += (__builtin_fabsf(f[b].y) == Tf) ? (1 << 16) : 0;
        ge_pack += (__builtin_fabsf(f[b].z) == Tf) ? (1 << 16) : 0;
        ge_pack += (__builtin_fabsf(f[b].w) == Tf) ? (1 << 16) : 0;
    }
    const int tot = dpp_reduce_add(ge_pack);
    const int cnt_gt = tot & 0xFFFF;
    const int r = K_SEL - cnt_gt;   // equals to keep, lowest global index first

    f32x4* op = reinterpret_cast<f32x4*>(out + row * D_DIM);
    const unsigned long long lt = (lane == 0) ? 0ull : (~0ull >> (64 - lane));
    int base = 0;  // equals in blocks b' < b   (global idx = 256*b + 4*lane + e)
    for (int b = 0; b < 8; ++b) {
        const float fe[4] = { f[b].x, f[b].y, f[b].z, f[b].w };
        unsigned long long m[4];
#pragma unroll
        for (int e = 0; e < 4; ++e) m[e] = __ballot(__builtin_fabsf(fe[e]) == Tf);
        int cm = 0;
#pragma unroll
        for (int e = 0; e < 4; ++e) cm += __popcll(m[e] & lt);
        f32x4 w;
        float wv[4];
        int partial = 0;
#pragma unroll
        for (int e = 0; e < 4; ++e) {
            const int rank = base + cm + partial;
            const bool eq = (__builtin_fabsf(fe[e]) == Tf);
            const bool sel = (__builtin_fabsf(fe[e]) > Tf) || (eq && rank < r);
            wv[e] = sel ? fe[e] * scale : 0.0f;
            partial += (int)((m[e] >> lane) & 1ull);
        }
        w.x = wv[0]; w.y = wv[1]; w.z = wv[2]; w.w = wv[3];
        __builtin_nontemporal_store(w, op + b * 64 + lane);
#pragma unroll
        for (int e = 0; e < 4; ++e) base += __popcll(m[e]);
    }
    if (lane == 0) thrws[row] = __uint_as_float(0xFF800000u);   // -inf: skip in K2
}

// ---------------- K2: streaming apply (copy-shaped) -------------------------
constexpr int AP_BLOCKS = 2048;

__global__ __launch_bounds__(NT) void apply_kernel(const float* __restrict__ x,
                                                   const float* __restrict__ thrws,
                                                   float* __restrict__ out,
                                                   long long n4) {
    const float scale = 2048.0f / 204.0f;
    const f32x4* xp = reinterpret_cast<const f32x4*>(x);
    f32x4* op = reinterpret_cast<f32x4*>(out);
    long long i = (long long)blockIdx.x * NT + threadIdx.x;
    const long long stride = (long long)AP_BLOCKS * NT;
#pragma unroll 4
    for (; i < n4; i += stride) {
        const int row = (int)(i >> 9);            // 512 float4 per row
        const float thr = thrws[row];             // wave-uniform (64 f4 <= row)
        const f32x4 v = xp[i];
        if (thr < 0.0f) continue;                 // rare: K1 wrote this row
        f32x4 w;
        w.x = (__builtin_fabsf(v.x) >= thr) ? v.x * scale : 0.0f;
        w.y = (__builtin_fabsf(v.y) >= thr) ? v.y * scale : 0.0f;
        w.z = (__builtin_fabsf(v.z) >= thr) ? v.z * scale : 0.0f;
        w.w = (__builtin_fabsf(v.w) >= thr) ? v.w * scale : 0.0f;
        __builtin_nontemporal_store(w, op + i);
    }
}

extern "C" void kernel_launch(void* const* d_in, const int* in_sizes, int n_in,
                              void* d_out, int out_size, void* d_ws, size_t ws_size,
                              hipStream_t stream) {
    const float* x = (const float*)d_in[0];
    float* out = (float*)d_out;
    float* thrws = (float*)d_ws;                     // rows * 4 B = 64 KB
    const int rows = in_sizes[0] / D_DIM;            // 16384
    const long long n4 = (long long)rows * (D_DIM / 4);

    thresh_kernel<<<rows / 4, NT, 0, stream>>>(x, out, thrws);
    apply_kernel<<<AP_BLOCKS, NT, 0, stream>>>(x, thrws, out, n4);
}

// Round 16
// 237.416 us; speedup vs baseline: 1.0384x; 1.0384x over previous
//
#include <hip/hip_runtime.h>

// SparseActivation: per row of D=2048 fp32, keep top K=204 by |x|, scale D/K.
//
// SMOOTH-ISSUE pipeline, attempt 2. R15 failed correctness; two suspects, both
// fixed here with zero change to the hypothesis under test:
//  (a) __launch_bounds__(NT,4) capped VGPR at 128 -> likely scratch spills.
//      Scratch ops are UNCOUNTED VMEM: they break the counted-vmcnt ledger
//      (VMWAIT(8) can retire against scratch, not our loads) and can spill a
//      pending-load register. Fix: (NT,2), the register regime R8 proved
//      (VGPR 80, passed). Actual usage <=128 still allows 4 blocks/CU.
//  (b) gload16 returned by value; the compiler copies r -> nbuf[s] believing
//      r is valid at asm-exit, so the copy can execute before data returns.
//      Fix: asm writes DIRECTLY into the destination ("=v"(dst)), no copy.
//
// Hypothesis (unchanged, 10 measured rounds): every clumped-burst structure
// runs 84-93us at ~2.3 TB/s while the harness fill kernel hits 6.7 TB/s; and
// R10's split showed even a READ-ONLY burst kernel caps near 2.3. Cause:
// chip-wide phase-aligned bursts — all waves share {16-op VMEM burst ->
// ~2000cy memory-silent search}; memory system idles ~65%. Fix under test:
// spread issue uniformly BY CONSTRUCTION — search = 8 fixed stages, each
// {issue ONE next-next-row load -> probe -> sched fence}.
//
// Pipeline: 4 rows/wave, 3 register buffers, depth 3. Loads-only vmcnt rule
// (R7 lesson): VMWAIT(N) guarantees load batch L retired iff N <= #LOADS
// issued after L (loads retire in order among loads; stores only inflate
// vmcnt -> stronger waits, never unsound). Steady state N=8; last row N=0.
// Grid: 1024 blocks, fully resident.
//
// Search: exact K-th largest via bracket bisection on |x| (free |src| mod on
// v_cmp). 3 warm-start stages near the N(0,1) expected K-th value (~1.648),
// then bisection; stages are fixed-count (loads issue unconditionally); a
// VALU-only tail finishes slow rows. Every bracket update is backed by an
// exact count -> exact for ANY finite input. Bracket closed to hi==lo+1 =>
// lo is the exact K-th pattern; boundary ties resolved by lowest-global-index
// ranking (matches lax.top_k stability).

constexpr int D_DIM = 2048;
constexpr int K_SEL = 204;     // int(2048 * 0.1)
constexpr int NT    = 256;     // 4 waves/block
constexpr int RPW   = 4;       // rows per wave

typedef float f32x4 __attribute__((ext_vector_type(4)));

// Pipeline-proof 16B load, writing DIRECTLY to the destination register(s):
// no intermediate value the compiler could copy before the data returns.
__device__ __forceinline__ void gload16(f32x4& dst, const f32x4* p) {
    asm volatile("global_load_dwordx4 %0, %1, off" : "=v"(dst) : "v"(p) : "memory");
}

// Counted wait + scheduler fence (rule #18).
#define VMWAIT(n)                                                  \
    do {                                                           \
        asm volatile("s_waitcnt vmcnt(" #n ")" ::: "memory");      \
        __builtin_amdgcn_sched_barrier(0);                         \
    } while (0)

#define SCHED_FENCE() __builtin_amdgcn_sched_barrier(0)

// Full-wave64 integer sum via DPP; returns total (uniform, via readlane 63).
__device__ __forceinline__ int dpp_reduce_add(int x) {
    x += __builtin_amdgcn_update_dpp(0, x, 0x111, 0xF, 0xF, true);  // row_shr:1
    x += __builtin_amdgcn_update_dpp(0, x, 0x112, 0xF, 0xF, true);  // row_shr:2
    x += __builtin_amdgcn_update_dpp(0, x, 0x114, 0xF, 0xF, true);  // row_shr:4
    x += __builtin_amdgcn_update_dpp(0, x, 0x118, 0xF, 0xF, true);  // row_shr:8
    x += __builtin_amdgcn_update_dpp(0, x, 0x142, 0xA, 0xF, false); // row_bcast:15
    x += __builtin_amdgcn_update_dpp(0, x, 0x143, 0xC, 0xF, false); // row_bcast:31
    return __builtin_amdgcn_readlane(x, 63);
}

// Exact wave-wide count of elements with |value| >= t (t > 0, finite data).
__device__ __forceinline__ int wave_count_ge(const f32x4 (&f)[8], float t) {
    int c0 = 0, c1 = 0, c2 = 0, c3 = 0;
#pragma unroll
    for (int b = 0; b < 8; ++b) {
        c0 += (__builtin_fabsf(f[b].x) >= t) ? 1 : 0;
        c1 += (__builtin_fabsf(f[b].y) >= t) ? 1 : 0;
        c2 += (__builtin_fabsf(f[b].z) >= t) ? 1 : 0;
        c3 += (__builtin_fabsf(f[b].w) >= t) ? 1 : 0;
    }
    return dpp_reduce_add((c0 + c1) + (c2 + c3));
}

// One exact probe: count(|x| >= t), update bracket / early-exit state.
__device__ __forceinline__ void probe_step(const f32x4 (&f)[8], unsigned t,
                                           unsigned& lo, unsigned& hi,
                                           unsigned& thr, bool& done) {
    const int c = wave_count_ge(f, __uint_as_float(t));
    if (c == K_SEL) { thr = t; done = true; }
    else if (c > K_SEL) lo = t; else hi = t;
}

// Process one row; if PF, issue exactly 8 prefetch loads into nbuf, one per
// stage, interleaved with the probe computation (smooth memory issue).
template <bool PF>
__device__ __forceinline__ void process_row(const f32x4 (&f)[8],
                                            f32x4 (&nbuf)[8],
                                            const f32x4* psrc,
                                            f32x4* op, const int lane) {
    const float scale = 2048.0f / 204.0f;

    // Bracket invariant: count(>= lo) > K > count(>= hi); count==K -> done.
    unsigned lo = 0u, hi = 0x80000000u;
    unsigned thr = 0u;
    bool done = false;

    // ---- 8 fixed stages: {1 prefetch load -> 1 probe -> fence} ------------
    if (PF) gload16(nbuf[0], psrc + 0 * 64 + lane);
    probe_step(f, 0x3FD30000u, lo, hi, thr, done);               // 1.6484375
    SCHED_FENCE();

    if (PF) gload16(nbuf[1], psrc + 1 * 64 + lane);
    if (!done)
        probe_step(f, (lo != 0u) ? 0x3FD60000u : 0x3FD00000u,    // 1.672/1.625
                   lo, hi, thr, done);
    SCHED_FENCE();

    if (PF) gload16(nbuf[2], psrc + 2 * 64 + lane);
    if (!done) {
        unsigned p3 = 0u;
        if (hi == 0x80000000u)      p3 = 0x3FE00000u;            // 1.75 (cap)
        else if (lo == 0u)          p3 = 0x3FC80000u;            // 1.5625 (floor)
        if (p3 != 0u) probe_step(f, p3, lo, hi, thr, done);
    }
    SCHED_FENCE();

    if (PF) gload16(nbuf[3], psrc + 3 * 64 + lane);
    if (!done) {
        if (lo == 0u)               probe_step(f, 0x3F800000u, lo, hi, thr, done);
        else if ((hi - lo) > 1u)    probe_step(f, (lo + hi) >> 1, lo, hi, thr, done);
    }
    SCHED_FENCE();

#pragma unroll
    for (int s = 4; s < 8; ++s) {
        if (PF) gload16(nbuf[s], psrc + s * 64 + lane);
        if (!done && (hi - lo) > 1u)
            probe_step(f, (lo + hi) >> 1, lo, hi, thr, done);
        SCHED_FENCE();
    }

    // ---- VALU-only tail: finish the bisection (no ledger interaction). ----
#pragma unroll 1
    while (!done && (hi - lo) > 1u)
        probe_step(f, (lo + hi) >> 1, lo, hi, thr, done);

    if (done) {
        // Exact top-K set == {|x| >= thr}; no tie handling needed.
        const float tf = __uint_as_float(thr);
#pragma unroll
        for (int b = 0; b < 8; ++b) {
            f32x4 w;
            w.x = (__builtin_fabsf(f[b].x) >= tf) ? f[b].x * scale : 0.0f;
            w.y = (__builtin_fabsf(f[b].y) >= tf) ? f[b].y * scale : 0.0f;
            w.z = (__builtin_fabsf(f[b].z) >= tf) ? f[b].z * scale : 0.0f;
            w.w = (__builtin_fabsf(f[b].w) >= tf) ? f[b].w * scale : 0.0f;
            __builtin_nontemporal_store(w, op + b * 64 + lane);
        }
        return;
    }

    // Bracket closed: lo is the exact K-th largest pattern
    // (count(>=lo) > K since lo never hit count==K, count(>lo)=count(>=hi)<K).
    const float Tf = __uint_as_float(lo);
    int ge_pack = 0;
#pragma unroll
    for (int b = 0; b < 8; ++b) {
        ge_pack += (__builtin_fabsf(f[b].x) > Tf) ? 1 : 0;
        ge_pack += (__builtin_fabsf(f[b].y) > Tf) ? 1 : 0;
        ge_pack += (__builtin_fabsf(f[b].z) > Tf) ? 1 : 0;
        ge_pack += (__builtin_fabsf(f[b].w) > Tf) ? 1 : 0;
        ge_pack += (__builtin_fabsf(f[b].x) == Tf) ? (1 << 16) : 0;
        ge_pack += (__builtin_fabsf(f[b].y) == Tf) ? (1 << 16) : 0;
        ge_pack += (__builtin_fabsf(f[b].z) == Tf) ? (1 << 16) : 0;
        ge_pack += (__builtin_fabsf(f[b].w) == Tf) ? (1 << 16) : 0;
    }
    const int tot = dpp_reduce_add(ge_pack);
    const int cnt_gt = tot & 0xFFFF;
    const int neq = tot >> 16;
    const int r = K_SEL - cnt_gt;   // equals to keep (1 <= r <= neq)

    if (neq == r) {
#pragma unroll
        for (int b = 0; b < 8; ++b) {
            f32x4 w;
            w.x = (__builtin_fabsf(f[b].x) >= Tf) ? f[b].x * scale : 0.0f;
            w.y = (__builtin_fabsf(f[b].y) >= Tf) ? f[b].y * scale : 0.0f;
            w.z = (__builtin_fabsf(f[b].z) >= Tf) ? f[b].z * scale : 0.0f;
            w.w = (__builtin_fabsf(f[b].w) >= Tf) ? f[b].w * scale : 0.0f;
            __builtin_nontemporal_store(w, op + b * 64 + lane);
        }
        return;
    }

    // Rare: among ==T keep the r with lowest global index
    // (matches lax.top_k stability). Rank via equality ballots.
    // Element (b, lane, e): global index = 256*b + 4*lane + e.
    const unsigned long long lt = (lane == 0) ? 0ull : (~0ull >> (64 - lane));
    int base = 0;  // equals in blocks b' < b
    for (int b = 0; b < 8; ++b) {
        const float fe[4] = { f[b].x, f[b].y, f[b].z, f[b].w };
        unsigned long long m[4];
#pragma unroll
        for (int e = 0; e < 4; ++e) m[e] = __ballot(__builtin_fabsf(fe[e]) == Tf);
        int cm = 0;  // equals in this block from lanes < lane
#pragma unroll
        for (int e = 0; e < 4; ++e) cm += __popcll(m[e] & lt);
        f32x4 w;
        float wv[4];
        int partial = 0;  // equals: same lane, e' < e
#pragma unroll
        for (int e = 0; e < 4; ++e) {
            const int rank = base + cm + partial;
            const bool eq = (__builtin_fabsf(fe[e]) == Tf);
            const bool sel = (__builtin_fabsf(fe[e]) > Tf) || (eq && rank < r);
            wv[e] = sel ? fe[e] * scale : 0.0f;
            partial += (int)((m[e] >> lane) & 1ull);
        }
        w.x = wv[0]; w.y = wv[1]; w.z = wv[2]; w.w = wv[3];
        __builtin_nontemporal_store(w, op + b * 64 + lane);
#pragma unroll
        for (int e = 0; e < 4; ++e) base += __popcll(m[e]);
    }
}

__global__ __launch_bounds__(NT, 2) void sparse_topk_kernel(
        const float* __restrict__ x, float* __restrict__ out) {
    const int wave = threadIdx.x >> 6;
    const int lane = threadIdx.x & 63;
    const long long gw = (long long)blockIdx.x * 4 + wave;   // global wave id
    const long long r0 = gw * RPW;

    const f32x4* xw = reinterpret_cast<const f32x4*>(x + r0 * D_DIM);
    f32x4* ow = reinterpret_cast<f32x4*>(out + r0 * D_DIM);

    f32x4 A[8], B[8], C[8];

    // Prologue: rows 0 and 1 in flight (16 loads outstanding).
#pragma unroll
    for (int b = 0; b < 8; ++b) gload16(A[b], xw + b * 64 + lane);
#pragma unroll
    for (int b = 0; b < 8; ++b) gload16(B[b], xw + 512 + b * 64 + lane);

    // Loads-only ledger: younger-of(batch k) = batch k+1 = 8 in steady state.
    VMWAIT(8); process_row<true >(A, C, xw + 1024, ow,            lane);  // row0, PF row2
    VMWAIT(8); process_row<true >(B, A, xw + 1536, ow + 512,      lane);  // row1, PF row3
    VMWAIT(8); process_row<false>(C, B, xw,        ow + 1024,     lane);  // row2
    VMWAIT(0); process_row<false>(A, B, xw,        ow + 1536,     lane);  // row3
}

extern "C" void kernel_launch(void* const* d_in, const int* in_sizes, int n_in,
                              void* d_out, int out_size, void* d_ws, size_t ws_size,
                              hipStream_t stream) {
    const float* x = (const float*)d_in[0];
    float* out = (float*)d_out;
    const int rows = in_sizes[0] / D_DIM;            // 16384
    sparse_topk_kernel<<<rows / (4 * RPW), NT, 0, stream>>>(x, out);
}